// Round 7
// baseline (82.548 us; speedup 1.0000x reference)
//
#include <hip/hip_runtime.h>

#define KS   13
#define HALF 6
#define TX   64
#define TY   64
#define S_H  76
#define S_P  84          // pitch (floats): rows shift 21 granule-slots -> even spread
#define NG   20          // staged float4 granules/row (80 floats: 8 halo + 64 + 8)
#define IMG_H 1024
#define IMG_W 1024

__device__ __forceinline__ int reflect_idx(int i, int n) {
    // single-bounce reflect (offsets <= 8 << n)
    if (i < 0) i = -i;
    if (i >= n) i = 2 * n - 2 - i;
    return i;
}

// H task (r, qq): outputs rel cols 16qq..16qq+15 from staged floats 16qq+2..16qq+29
// (granules 4qq..4qq+7). Reads only; write-back is a separate step after a barrier.
__device__ __forceinline__ void h_read_compute(const float (*s)[S_P], const float* g,
                                               int r, int qq, float* acc) {
    const int base = 16 * qq;
    float w[32];
    #pragma unroll
    for (int k = 0; k < 8; ++k) {
        float4 v = *reinterpret_cast<const float4*>(&s[r][base + 4 * k]);
        w[4*k+0] = v.x; w[4*k+1] = v.y; w[4*k+2] = v.z; w[4*k+3] = v.w;
    }
    #pragma unroll
    for (int u = 0; u < 16; ++u) acc[u] = 0.0f;
    #pragma unroll
    for (int j = 0; j < KS; ++j) {
        #pragma unroll
        for (int u = 0; u < 16; ++u)
            acc[u] += g[j] * w[u + 2 + j];
    }
}

__device__ __forceinline__ void h_write(float (*s)[S_P], int r, int qq, const float* acc) {
    const int base = 8 + 16 * qq;   // H row r -> s[r][8..71]
    #pragma unroll
    for (int k = 0; k < 4; ++k)
        *reinterpret_cast<float4*>(&s[r][base + 4 * k]) =
            make_float4(acc[4*k], acc[4*k+1], acc[4*k+2], acc[4*k+3]);
}

// No min-waves bound: (256,6) capped VGPRs at 40 -> 543 MB scratch spill (R2).
__global__ __launch_bounds__(256) void gauss_blur_fused(
    const float* __restrict__ x, const float* __restrict__ k2d,
    float* __restrict__ out)
{
    __shared__ float s[S_H][S_P];   // 25536 B -> 6 blocks/CU

    const int tid = threadIdx.x;
    const int bx  = blockIdx.x;
    const int ox  = bx * TX;
    const int oy  = blockIdx.y * TY;
    const int img = blockIdx.z;

    const float* xin = x + (size_t)img * IMG_H * IMG_W;
    float*       o   = out + (size_t)img * IMG_H * IMG_W;

    // per-thread 1D taps: k2d = outer(g,g), g[i] = k2d[i][6]/sqrt(k2d[6][6])
    float g[KS];
    {
        float c   = k2d[HALF * KS + HALF];
        float inv = 1.0f / sqrtf(c);
        #pragma unroll
        for (int j = 0; j < KS; ++j) g[j] = k2d[j * KS + HALF] * inv;
    }

    const bool interior = (bx > 0) && (bx < (IMG_W / TX) - 1);

    // ---- Stage: global -> s, coalesced float4. s[r][i] = x[refl(oy+r-6)][ox-8+i] ----
    #pragma unroll
    for (int t = 0; t < 6; ++t) {
        int idx = tid + t * 256;
        if (idx < S_H * NG) {
            int r   = idx / NG;
            int c4  = idx - r * NG;
            int gr  = reflect_idx(oy + r - HALF, IMG_H);
            const float* row = xin + (size_t)gr * IMG_W;
            int gc0 = ox - 8 + c4 * 4;
            float4 v;
            if (interior) {
                v = *reinterpret_cast<const float4*>(row + gc0);
            } else {
                v.x = row[reflect_idx(gc0 + 0, IMG_W)];
                v.y = row[reflect_idx(gc0 + 1, IMG_W)];
                v.z = row[reflect_idx(gc0 + 2, IMG_W)];
                v.w = row[reflect_idx(gc0 + 3, IMG_W)];
            }
            *reinterpret_cast<float4*>(&s[r][c4 * 4]) = v;
        }
    }
    __syncthreads();

    // ---- H pass, 16 outputs/task, 304 tasks. ALL reads before ONE barrier, then
    // ALL writes (in place; destinations disjoint). No intra-wave RAW/WAR games —
    // the lockstep variant had a cross-lane WAR hazard the compiler could expose.
    const int  rA   = tid >> 2;
    const int  qqA  = tid & 3;
    const bool hasB = tid < 48;
    const int  rB   = 64 + (tid >> 2);

    float acc[16], acc2[16];
    h_read_compute(s, g, rA, qqA, acc);
    if (hasB) h_read_compute(s, g, rB, qqA, acc2);
    __syncthreads();
    h_write(s, rA, qqA, acc);
    if (hasB) h_write(s, rB, qqA, acc2);
    __syncthreads();

    // ---- V pass: 128 tasks, 8 rows x 4 cols each (20 reads / 32 outputs) ----
    if (tid < 128) {
        int q  = tid & 15;          // col granule
        int rg = tid >> 4;          // row group 0..7
        int c  = 8 + 4 * q;
        int rb = rg * 8;

        float4 vacc[8];
        #pragma unroll
        for (int ii = 0; ii < 8; ++ii) vacc[ii] = make_float4(0, 0, 0, 0);

        #pragma unroll
        for (int i = 0; i < 20; ++i) {   // staged rows rb .. rb+19
            float4 v = *reinterpret_cast<const float4*>(&s[rb + i][c]);
            #pragma unroll
            for (int ii = 0; ii < 8; ++ii) {
                int j = i - ii;
                if (j >= 0 && j < KS) {
                    vacc[ii].x += g[j] * v.x;
                    vacc[ii].y += g[j] * v.y;
                    vacc[ii].z += g[j] * v.z;
                    vacc[ii].w += g[j] * v.w;
                }
            }
        }

        #pragma unroll
        for (int ii = 0; ii < 8; ++ii)
            *reinterpret_cast<float4*>(o + (size_t)(oy + rb + ii) * IMG_W + ox + 4 * q) = vacc[ii];
    }
}

extern "C" void kernel_launch(void* const* d_in, const int* in_sizes, int n_in,
                              void* d_out, int out_size, void* d_ws, size_t ws_size,
                              hipStream_t stream) {
    const float* x   = (const float*)d_in[0];
    const float* k2d = (const float*)d_in[1];
    float*       out = (float*)d_out;

    dim3 grid(IMG_W / TX, IMG_H / TY, 32);  // 16 x 16 x 32 = 8192 blocks
    gauss_blur_fused<<<grid, 256, 0, stream>>>(x, k2d, out);
}